// Round 2
// baseline (605.576 us; speedup 1.0000x reference)
//
#include <hip/hip_runtime.h>
#include <stdint.h>

#define B_   16
#define L_   2048
#define D_   256
#define NROW (B_*L_)

#define EPAD 40    // Es row stride (shorts)
#define TPAD 66    // qkv transpose buffer row stride

typedef __attribute__((ext_vector_type(8))) short s8v;   // 8 x bf16 (as shorts)
typedef __attribute__((ext_vector_type(4))) float f4v;   // MFMA accumulator
typedef __attribute__((ext_vector_type(4))) float f4n;   // native float4 for NT stores

__device__ __forceinline__ unsigned short f2b(float f) {   // RNE f32->bf16
    unsigned u = __builtin_bit_cast(unsigned, f);
    return (unsigned short)((u + 0x7fffu + ((u >> 16) & 1u)) >> 16);
}

// HW packed f32->bf16 (RNE): d.lo = bf16(a), d.hi = bf16(b). 1 inst vs ~8.
__device__ __forceinline__ unsigned cvtpk(float a, float b) {
    unsigned r;
    asm("v_cvt_pk_bf16_f32 %0, %1, %2" : "=v"(r) : "v"(a), "v"(b));
    return r;
}

// async global->LDS, 16B per lane; LDS dest = wave-uniform base + lane*16
__device__ __forceinline__ void gl16(const void* g, void* l) {
    __builtin_amdgcn_global_load_lds(
        (const __attribute__((address_space(1))) unsigned int*)g,
        (__attribute__((address_space(3))) unsigned int*)l, 16, 0, 0);
}

// ---------------- K1: QKV projection ----------------
// grid (512 row-blocks, 2 types), block 256 (4 waves).
// type0: Q from x.  type1: K and V from y (y staged once).
// Xs/Ws reads XOR-swizzled in 16B chunks to kill pow2-stride bank conflicts.
__global__ __launch_bounds__(256) void qkv_kernel(
    const float* __restrict__ x, const float* __restrict__ y,
    const float* __restrict__ Wq, const float* __restrict__ Wk, const float* __restrict__ Wv,
    unsigned short* __restrict__ Qb, unsigned short* __restrict__ Kb,
    unsigned short* __restrict__ Vt,
    float* __restrict__ qn, float* __restrict__ kn)
{
    __shared__ unsigned short Xs[64*256];    // 32 KB input tile (bf16)
    __shared__ unsigned short Ws[64*256];    // 32 KB weight tile (bf16)
    __shared__ unsigned short Ts[64*TPAD];   // V transpose buffer

    const int t    = threadIdx.x;
    const int r0   = blockIdx.x * 64;   // global row (flat b*L + pos)
    const int type = blockIdx.y;        // 0=Q  1=K+V

    const float* X = type ? y : x;

    // Stage X tile [64][256] fp32 -> bf16 LDS, 16B-chunk swizzled by row&15.
    #pragma unroll
    for (int p = 0; p < 16; ++p) {
        int idx  = p*256 + t;
        int row  = idx >> 6;
        int half = idx & 1;              // which 8B half of the 16B chunk
        int blk  = (idx & 63) >> 1;      // 16B chunk index 0..31
        int c4   = blk*8 + half*4;       // source column (shorts/floats)
        float4 vx = *(const float4*)(X + (size_t)(r0+row)*D_ + c4);
        uint2 px;
        px.x = cvtpk(vx.x, vx.y);
        px.y = cvtpk(vx.z, vx.w);
        *(uint2*)(Xs + row*256 + (blk ^ (row & 15))*8 + half*4) = px;
    }

    const int w = t >> 6, lane = t & 63, q16 = lane & 15, quad = lane >> 4;
    const int m0 = w * 16;   // wave's 16-row band

    float p4[4] = {0.f, 0.f, 0.f, 0.f};   // row-norm partials (Q/K)
    const f4v z4 = {0.f, 0.f, 0.f, 0.f};

    for (int ct = 0; ct < 4; ++ct) {
        const int e0 = ct * 64;

        // ---- Q (type0) or K (type1) weight tile ----
        __syncthreads();   // previous tile's readers done (covers Xs stage on ct=0)
        {
            const float* W = type ? Wk : Wq;
            #pragma unroll
            for (int p = 0; p < 16; ++p) {
                int idx  = p*256 + t;
                int row  = idx >> 6;
                int half = idx & 1;
                int blk  = (idx & 63) >> 1;
                int c4   = blk*8 + half*4;
                float4 vw = *(const float4*)(W + (size_t)(e0+row)*D_ + c4);
                uint2 pw;
                pw.x = cvtpk(vw.x, vw.y);
                pw.y = cvtpk(vw.z, vw.w);
                *(uint2*)(Ws + row*256 + (blk ^ (row & 15))*8 + half*4) = pw;
            }
        }
        __syncthreads();

        f4v acc[4];
        #pragma unroll
        for (int n = 0; n < 4; ++n) acc[n] = z4;
        #pragma unroll
        for (int c = 0; c < 8; ++c) {
            s8v a = *(const s8v*)(Xs + (m0 + q16)*256 + (((c*4+quad) ^ q16)*8));
            #pragma unroll
            for (int n = 0; n < 4; ++n) {
                s8v bb = *(const s8v*)(Ws + (n*16 + q16)*256 + (((c*4+quad) ^ q16)*8));
                acc[n] = __builtin_amdgcn_mfma_f32_16x16x32_bf16(a, bb, acc[n], 0, 0, 0);
            }
        }
        {
            unsigned short* Out = type ? Kb : Qb;
            // C-layout: value at (row = quad*4+r, col = n*16+q16)
            #pragma unroll
            for (int n = 0; n < 4; ++n)
                #pragma unroll
                for (int r = 0; r < 4; ++r) {
                    float v = acc[n][r];
                    p4[r] += v * v;
                    Out[(size_t)(r0 + m0 + quad*4 + r)*D_ + e0 + n*16 + q16] = f2b(v);
                }
        }

        if (type) {
            // ---- V weight tile ----
            __syncthreads();   // K-mfma readers of Ws done
            #pragma unroll
            for (int p = 0; p < 16; ++p) {
                int idx  = p*256 + t;
                int row  = idx >> 6;
                int half = idx & 1;
                int blk  = (idx & 63) >> 1;
                int c4   = blk*8 + half*4;
                float4 vw = *(const float4*)(Wv + (size_t)(e0+row)*D_ + c4);
                uint2 pw;
                pw.x = cvtpk(vw.x, vw.y);
                pw.y = cvtpk(vw.z, vw.w);
                *(uint2*)(Ws + row*256 + (blk ^ (row & 15))*8 + half*4) = pw;
            }
            __syncthreads();

            f4v vacc[4];
            #pragma unroll
            for (int n = 0; n < 4; ++n) vacc[n] = z4;
            #pragma unroll
            for (int c = 0; c < 8; ++c) {
                s8v a = *(const s8v*)(Xs + (m0 + q16)*256 + (((c*4+quad) ^ q16)*8));
                #pragma unroll
                for (int n = 0; n < 4; ++n) {
                    s8v bb = *(const s8v*)(Ws + (n*16 + q16)*256 + (((c*4+quad) ^ q16)*8));
                    vacc[n] = __builtin_amdgcn_mfma_f32_16x16x32_bf16(a, bb, vacc[n], 0, 0, 0);
                }
            }
            // transpose via LDS, write Vt[b][d][k] coalesced
            #pragma unroll
            for (int n = 0; n < 4; ++n)
                #pragma unroll
                for (int r = 0; r < 4; ++r)
                    Ts[(m0 + quad*4 + r)*TPAD + n*16 + q16] = f2b(vacc[n][r]);
            __syncthreads();
            int j    = t >> 2;   // local d col 0..63
            int kseg = t & 3;    // 16 k's each
            unsigned pk[8];
            #pragma unroll
            for (int i = 0; i < 8; ++i) {
                unsigned lo = Ts[(kseg*16 + 2*i    )*TPAD + j];
                unsigned hi = Ts[(kseg*16 + 2*i + 1)*TPAD + j];
                pk[i] = lo | (hi << 16);
            }
            int bb_ = r0 >> 11;         // batch index
            int k0g = r0 & (L_ - 1);    // k offset within batch
            unsigned short* dst = Vt + (size_t)(bb_*D_ + e0 + j)*L_ + k0g + kseg*16;
            *(uint4*)dst       = make_uint4(pk[0], pk[1], pk[2], pk[3]);
            *((uint4*)dst + 1) = make_uint4(pk[4], pk[5], pk[6], pk[7]);
        }
    }

    {
        float* norm = type ? kn : qn;
        #pragma unroll
        for (int r = 0; r < 4; ++r) {
            float v = p4[r];
            v += __shfl_xor(v, 1, 16);
            v += __shfl_xor(v, 2, 16);
            v += __shfl_xor(v, 4, 16);
            v += __shfl_xor(v, 8, 16);
            if (q16 == 0) norm[r0 + m0 + quad*4 + r] = v;
        }
    }
}

// ---- staging helpers (DMA direct to LDS, XOR-swizzled global src) ----
// Ks: 32 rows x 256 cols bf16; 16B chunk blk stored at global blk^(row&15)
__device__ __forceinline__ void stage_K(const unsigned short* Kb, unsigned short* ks,
                                        int bk, int k0, int w, int lane) {
    #pragma unroll
    for (int p = 0; p < 4; ++p) {
        int slot = p*256 + w*64 + lane;
        int row  = slot >> 5;
        int blk  = slot & 31;
        gl16(Kb + (size_t)(bk + k0 + row)*D_ + ((blk ^ (row & 15))*8),
             ks + (size_t)(p*256 + w*64)*8);
    }
}
// Vs: 256 rows(d) x 32 cols(k) bf16; chunk blk (0..3) swizzled by (d>>1)&3
__device__ __forceinline__ void stage_V(const unsigned short* Vt, unsigned short* vs,
                                        int bD, int k0, int w, int lane) {
    #pragma unroll
    for (int p = 0; p < 4; ++p) {
        int slot = p*256 + w*64 + lane;
        int d    = slot >> 2;
        int blk  = slot & 3;
        gl16(Vt + (size_t)(bD + d)*L_ + k0 + ((blk ^ ((d >> 1) & 3))*8),
             vs + (size_t)(p*256 + w*64)*8);
    }
}

// -------- K2: single transcendental pass + fused normalize --------
// grid (32 qb, 16 b) = 512 blocks (2/CU, 8 waves/CU), wave owns 16 q rows.
// XCD-swizzled so each XCD owns 2 consecutive batches -> K/V L2-resident.
// Per k-tile: QK MFMA -> E = exp(exp(-dist)) (once!) -> rowsum (regs) ->
// Es LDS roundtrip -> PV MFMA -> stream E bf16 (row-major) to global.
// Epilogue: rowsum -> att_out (scaled by 1/rs) -> normalize sweep of Eb
// (former norm_kernel, fused: saves launch + rowsum roundtrip, NT stores).
__global__ __launch_bounds__(256) void attnpv_kernel(
    const unsigned short* __restrict__ Qb, const unsigned short* __restrict__ Kb,
    const unsigned short* __restrict__ Vt,
    const float* __restrict__ qn, const float* __restrict__ kn,
    const unsigned char* __restrict__ mask,
    unsigned short* __restrict__ Eb,
    float* __restrict__ att_out, float* __restrict__ attn)
{
    __shared__ unsigned short Ks[2][32*256];    // 16 KB each
    __shared__ unsigned short Vs[2][256*32];    // 16 KB each
    __shared__ unsigned short Es[4][16*EPAD];   // per-wave E tile (5 KB)
    __shared__ float invsh[4][16];              // per-row 1/rowsum for sweep

    const int t  = threadIdx.x;
    // XCD-aware bijective swizzle: dispatch-linear s -> XCD s&7 (round-robin).
    // b = (s&7)*2 + (s>>8): each XCD runs exactly 2 batches -> K/V ws = 4 MB = L2.
    const int s  = blockIdx.y * 32 + blockIdx.x;
    const int b  = ((s & 7) << 1) | (s >> 8);
    const int q0 = ((s >> 3) & 31) * 64;
    const int bk = b * L_;
    const int bD = b * D_;
    const int w = t >> 6, lane = t & 63, q16 = lane & 15, quad = lane >> 4;

    const int qrow = bk + q0 + w*16;
    s8v qa[8];
    float qnr[4];
    #pragma unroll
    for (int c = 0; c < 8; ++c)
        qa[c] = *(const s8v*)(Qb + (size_t)(qrow + q16)*D_ + c*32 + quad*8);
    #pragma unroll
    for (int r = 0; r < 4; ++r)
        qnr[r] = qn[qrow + quad*4 + r];

    // E-export addressing: lane -> (row = lane>>2, colseg = lane&3)
    unsigned short* ebase = Eb + (size_t)(qrow + (lane >> 2))*L_ + (lane & 3)*8;
    const unsigned short* esrc = &Es[w][(lane >> 2)*EPAD + (lane & 3)*8];

    float rs[4] = {0.f, 0.f, 0.f, 0.f};
    const f4v z4 = {0.f, 0.f, 0.f, 0.f};
    f4v O[16];
    #pragma unroll
    for (int n = 0; n < 16; ++n) O[n] = z4;

    stage_K(Kb, Ks[0], bk, 0, w, lane);
    stage_V(Vt, Vs[0], bD, 0, w, lane);
    for (int kt = 0; kt < 64; ++kt) {
        const int k0 = kt * 32;
        const int cur = kt & 1;
        __syncthreads();                       // Ks/Vs[cur] ready; prev bufs free
        if (kt < 63) {
            stage_K(Kb, Ks[cur ^ 1], bk, k0 + 32, w, lane);
            stage_V(Vt, Vs[cur ^ 1], bD, k0 + 32, w, lane);
        }

        float kcv[2]; int mkv[2];
        #pragma unroll
        for (int n = 0; n < 2; ++n) {
            kcv[n] = kn[bk + k0 + n*16 + q16];
            mkv[n] = mask[bk + k0 + n*16 + q16];
        }

        #pragma unroll
        for (int n = 0; n < 2; ++n) {
            f4v s4 = {0.f, 0.f, 0.f, 0.f};
            __builtin_amdgcn_s_setprio(1);
            #pragma unroll
            for (int c = 0; c < 8; ++c) {
                s8v bb = *(const s8v*)(Ks[cur] + (n*16 + q16)*256 + (((c*4+quad) ^ q16)*8));
                s4 = __builtin_amdgcn_mfma_f32_16x16x32_bf16(qa[c], bb, s4, 0, 0, 0);
            }
            __builtin_amdgcn_s_setprio(0);
            #pragma unroll
            for (int r = 0; r < 4; ++r) {
                float d2 = qnr[r] + kcv[n] - 2.0f * s4[r];
                float dist = sqrtf(fmaxf(d2, 0.f));
                float E = mkv[n] ? 0.f : __expf(__expf(-dist));
                rs[r] += E;
                Es[w][(quad*4 + r)*EPAD + n*16 + q16] = f2b(E);
            }
        }
        // PV: A = own-wave Es (same-wave write->read, lgkmcnt ordered)
        s8v af = *(const s8v*)(&Es[w][q16*EPAD + quad*8]);
        __builtin_amdgcn_s_setprio(1);
        #pragma unroll
        for (int n = 0; n < 16; ++n) {
            s8v vb = *(const s8v*)(Vs[cur] + (n*16 + q16)*32 +
                                   ((quad ^ ((q16 >> 1) & 3))*8));
            O[n] = __builtin_amdgcn_mfma_f32_16x16x32_bf16(af, vb, O[n], 0, 0, 0);
        }
        __builtin_amdgcn_s_setprio(0);
        // stream E tile (row-major, bf16) to global for the normalize sweep
        *(s8v*)(ebase + k0) = *(const s8v*)esrc;
    }

    // rowsum (complete: block covered all k); butterfly leaves sum in all lanes
    float inv4[4];
    #pragma unroll
    for (int r = 0; r < 4; ++r) {
        float v = rs[r];
        v += __shfl_xor(v, 1, 16);
        v += __shfl_xor(v, 2, 16);
        v += __shfl_xor(v, 4, 16);
        v += __shfl_xor(v, 8, 16);
        inv4[r] = 1.0f / v;
        if (q16 == 0) invsh[w][quad*4 + r] = inv4[r];
    }

    #pragma unroll
    for (int n = 0; n < 16; ++n)
        #pragma unroll
        for (int r = 0; r < 4; ++r)
            __builtin_nontemporal_store(O[n][r] * inv4[r],
                att_out + (size_t)(qrow + quad*4 + r)*D_ + n*16 + q16);

    // drain all E exports (barrier implies vmcnt(0)) before the read-back sweep
    __syncthreads();

    // ---- fused normalize: attn = Eb * (1/rowsum)  (was norm_kernel) ----
    // wave w sweeps its own 16 rows: lane -> (row = lane>>2, colseg = lane&3)
    {
        const int rloc = lane >> 2, cseg = lane & 3;
        const float invr = invsh[w][rloc];
        const unsigned short* erow = Eb + (size_t)(qrow + rloc)*L_;
        float* arow = attn + (size_t)(qrow + rloc)*L_;
        #pragma unroll 4
        for (int it = 0; it < 64; ++it) {
            const int c0 = it*32 + cseg*8;
            s8v e = *(const s8v*)(erow + c0);
            f4n o0, o1;
            o0.x = __builtin_bit_cast(float, ((unsigned)(unsigned short)e[0]) << 16) * invr;
            o0.y = __builtin_bit_cast(float, ((unsigned)(unsigned short)e[1]) << 16) * invr;
            o0.z = __builtin_bit_cast(float, ((unsigned)(unsigned short)e[2]) << 16) * invr;
            o0.w = __builtin_bit_cast(float, ((unsigned)(unsigned short)e[3]) << 16) * invr;
            o1.x = __builtin_bit_cast(float, ((unsigned)(unsigned short)e[4]) << 16) * invr;
            o1.y = __builtin_bit_cast(float, ((unsigned)(unsigned short)e[5]) << 16) * invr;
            o1.z = __builtin_bit_cast(float, ((unsigned)(unsigned short)e[6]) << 16) * invr;
            o1.w = __builtin_bit_cast(float, ((unsigned)(unsigned short)e[7]) << 16) * invr;
            __builtin_nontemporal_store(o0, (f4n*)(arow + c0));
            __builtin_nontemporal_store(o1, (f4n*)(arow + c0 + 4));
        }
    }
}

extern "C" void kernel_launch(void* const* d_in, const int* in_sizes, int n_in,
                              void* d_out, int out_size, void* d_ws, size_t ws_size,
                              hipStream_t stream) {
    (void)in_sizes; (void)n_in; (void)out_size; (void)ws_size;
    const float* x  = (const float*)d_in[0];
    const float* y  = (const float*)d_in[1];
    const unsigned char* mask = (const unsigned char*)d_in[2];
    const float* Wq = (const float*)d_in[3];
    const float* Wk = (const float*)d_in[4];
    const float* Wv = (const float*)d_in[5];

    // ws: Qb | Kb | Vt (bf16) | qn | kn (fp32) | Eb (bf16, 134 MB)
    char* ws = (char*)d_ws;
    unsigned short* Qb = (unsigned short*)ws;
    unsigned short* Kb = Qb + (size_t)NROW * D_;
    unsigned short* Vt = Kb + (size_t)NROW * D_;
    float* qn     = (float*)(ws + 3 * (size_t)NROW * D_ * 2);
    float* kn     = qn + NROW;
    unsigned short* Eb = (unsigned short*)(kn + NROW);

    float* att_out = (float*)d_out;                       // [B, LQ, D]
    float* attn    = att_out + (size_t)NROW * D_;         // [B, LQ, LK]

    qkv_kernel<<<dim3(512, 2), 256, 0, stream>>>(x, y, Wq, Wk, Wv,
                                                 Qb, Kb, Vt, qn, kn);
    attnpv_kernel<<<dim3(32, 16), 256, 0, stream>>>(Qb, Kb, Vt, qn, kn, mask,
                                                    Eb, att_out, attn);
}

// Round 3
// 575.254 us; speedup vs baseline: 1.0527x; 1.0527x over previous
//
#include <hip/hip_runtime.h>
#include <stdint.h>

#define B_   16
#define L_   2048
#define D_   256
#define NROW (B_*L_)

#define EPAD 40    // Es row stride (shorts)
#define TPAD 66    // qkv transpose buffer row stride

typedef __attribute__((ext_vector_type(8))) short s8v;   // 8 x bf16 (as shorts)
typedef __attribute__((ext_vector_type(4))) float f4v;   // MFMA accumulator
typedef __attribute__((ext_vector_type(4))) float f4n;   // native float4 (NT stores)

__device__ __forceinline__ unsigned short f2b(float f) {   // RNE f32->bf16
    unsigned u = __builtin_bit_cast(unsigned, f);
    return (unsigned short)((u + 0x7fffu + ((u >> 16) & 1u)) >> 16);
}

// HW packed f32->bf16 (RNE): d.lo = bf16(a), d.hi = bf16(b)
__device__ __forceinline__ unsigned cvtpk(float a, float b) {
    unsigned r;
    asm("v_cvt_pk_bf16_f32 %0, %1, %2" : "=v"(r) : "v"(a), "v"(b));
    return r;
}

// async global->LDS, 16B per lane; LDS dest = wave-uniform base + lane*16
__device__ __forceinline__ void gl16(const void* g, void* l) {
    __builtin_amdgcn_global_load_lds(
        (const __attribute__((address_space(1))) unsigned int*)g,
        (__attribute__((address_space(3))) unsigned int*)l, 16, 0, 0);
}

// ---------------- K1: QKV projection ----------------
__global__ __launch_bounds__(256) void qkv_kernel(
    const float* __restrict__ x, const float* __restrict__ y,
    const float* __restrict__ Wq, const float* __restrict__ Wk, const float* __restrict__ Wv,
    unsigned short* __restrict__ Qb, unsigned short* __restrict__ Kb,
    unsigned short* __restrict__ Vt,
    float* __restrict__ qn, float* __restrict__ kn)
{
    __shared__ unsigned short Xs[64*256];    // 32 KB input tile (bf16)
    __shared__ unsigned short Ws[64*256];    // 32 KB weight tile (bf16)
    __shared__ unsigned short Ts[64*TPAD];   // V transpose buffer

    const int t    = threadIdx.x;
    const int r0   = blockIdx.x * 64;   // global row (flat b*L + pos)
    const int type = blockIdx.y;        // 0=Q  1=K+V

    const float* X = type ? y : x;

    #pragma unroll
    for (int p = 0; p < 16; ++p) {
        int idx  = p*256 + t;
        int row  = idx >> 6;
        int half = idx & 1;
        int blk  = (idx & 63) >> 1;
        int c4   = blk*8 + half*4;
        float4 vx = *(const float4*)(X + (size_t)(r0+row)*D_ + c4);
        uint2 px;
        px.x = cvtpk(vx.x, vx.y);
        px.y = cvtpk(vx.z, vx.w);
        *(uint2*)(Xs + row*256 + (blk ^ (row & 15))*8 + half*4) = px;
    }

    const int w = t >> 6, lane = t & 63, q16 = lane & 15, quad = lane >> 4;
    const int m0 = w * 16;

    float p4[4] = {0.f, 0.f, 0.f, 0.f};
    const f4v z4 = {0.f, 0.f, 0.f, 0.f};

    for (int ct = 0; ct < 4; ++ct) {
        const int e0 = ct * 64;

        __syncthreads();
        {
            const float* W = type ? Wk : Wq;
            #pragma unroll
            for (int p = 0; p < 16; ++p) {
                int idx  = p*256 + t;
                int row  = idx >> 6;
                int half = idx & 1;
                int blk  = (idx & 63) >> 1;
                int c4   = blk*8 + half*4;
                float4 vw = *(const float4*)(W + (size_t)(e0+row)*D_ + c4);
                uint2 pw;
                pw.x = cvtpk(vw.x, vw.y);
                pw.y = cvtpk(vw.z, vw.w);
                *(uint2*)(Ws + row*256 + (blk ^ (row & 15))*8 + half*4) = pw;
            }
        }
        __syncthreads();

        f4v acc[4];
        #pragma unroll
        for (int n = 0; n < 4; ++n) acc[n] = z4;
        #pragma unroll
        for (int c = 0; c < 8; ++c) {
            s8v a = *(const s8v*)(Xs + (m0 + q16)*256 + (((c*4+quad) ^ q16)*8));
            #pragma unroll
            for (int n = 0; n < 4; ++n) {
                s8v bb = *(const s8v*)(Ws + (n*16 + q16)*256 + (((c*4+quad) ^ q16)*8));
                acc[n] = __builtin_amdgcn_mfma_f32_16x16x32_bf16(a, bb, acc[n], 0, 0, 0);
            }
        }
        {
            unsigned short* Out = type ? Kb : Qb;
            #pragma unroll
            for (int n = 0; n < 4; ++n)
                #pragma unroll
                for (int r = 0; r < 4; ++r) {
                    float v = acc[n][r];
                    p4[r] += v * v;
                    Out[(size_t)(r0 + m0 + quad*4 + r)*D_ + e0 + n*16 + q16] = f2b(v);
                }
        }

        if (type) {
            __syncthreads();
            #pragma unroll
            for (int p = 0; p < 16; ++p) {
                int idx  = p*256 + t;
                int row  = idx >> 6;
                int half = idx & 1;
                int blk  = (idx & 63) >> 1;
                int c4   = blk*8 + half*4;
                float4 vw = *(const float4*)(Wv + (size_t)(e0+row)*D_ + c4);
                uint2 pw;
                pw.x = cvtpk(vw.x, vw.y);
                pw.y = cvtpk(vw.z, vw.w);
                *(uint2*)(Ws + row*256 + (blk ^ (row & 15))*8 + half*4) = pw;
            }
            __syncthreads();

            f4v vacc[4];
            #pragma unroll
            for (int n = 0; n < 4; ++n) vacc[n] = z4;
            #pragma unroll
            for (int c = 0; c < 8; ++c) {
                s8v a = *(const s8v*)(Xs + (m0 + q16)*256 + (((c*4+quad) ^ q16)*8));
                #pragma unroll
                for (int n = 0; n < 4; ++n) {
                    s8v bb = *(const s8v*)(Ws + (n*16 + q16)*256 + (((c*4+quad) ^ q16)*8));
                    vacc[n] = __builtin_amdgcn_mfma_f32_16x16x32_bf16(a, bb, vacc[n], 0, 0, 0);
                }
            }
            #pragma unroll
            for (int n = 0; n < 4; ++n)
                #pragma unroll
                for (int r = 0; r < 4; ++r)
                    Ts[(m0 + quad*4 + r)*TPAD + n*16 + q16] = f2b(vacc[n][r]);
            __syncthreads();
            int j    = t >> 2;
            int kseg = t & 3;
            unsigned pk[8];
            #pragma unroll
            for (int i = 0; i < 8; ++i) {
                unsigned lo = Ts[(kseg*16 + 2*i    )*TPAD + j];
                unsigned hi = Ts[(kseg*16 + 2*i + 1)*TPAD + j];
                pk[i] = lo | (hi << 16);
            }
            int bb_ = r0 >> 11;
            int k0g = r0 & (L_ - 1);
            unsigned short* dst = Vt + (size_t)(bb_*D_ + e0 + j)*L_ + k0g + kseg*16;
            *(uint4*)dst       = make_uint4(pk[0], pk[1], pk[2], pk[3]);
            *((uint4*)dst + 1) = make_uint4(pk[4], pk[5], pk[6], pk[7]);
        }
    }

    {
        float* norm = type ? kn : qn;
        #pragma unroll
        for (int r = 0; r < 4; ++r) {
            float v = p4[r];
            v += __shfl_xor(v, 1, 16);
            v += __shfl_xor(v, 2, 16);
            v += __shfl_xor(v, 4, 16);
            v += __shfl_xor(v, 8, 16);
            if (q16 == 0) norm[r0 + m0 + quad*4 + r] = v;
        }
    }
}

// ---- staging helpers for 8-wave (512 thr) blocks ----
// Ks tile: 32 rows x 256 cols bf16 (16 KB) = 1024 x 16B chunks, 2 per lane
__device__ __forceinline__ void stage_K(const unsigned short* Kb, unsigned short* ks,
                                        int bk, int k0, int w, int lane) {
    #pragma unroll
    for (int p = 0; p < 2; ++p) {
        int slot = p*512 + w*64 + lane;
        int row  = slot >> 5;
        int blk  = slot & 31;
        gl16(Kb + (size_t)(bk + k0 + row)*D_ + ((blk ^ (row & 15))*8),
             ks + (size_t)(p*512 + w*64)*8);
    }
}
// Vs tile: 256 rows(d) x 32 cols(k) bf16 (16 KB)
__device__ __forceinline__ void stage_V(const unsigned short* Vt, unsigned short* vs,
                                        int bD, int k0, int w, int lane) {
    #pragma unroll
    for (int p = 0; p < 2; ++p) {
        int slot = p*512 + w*64 + lane;
        int d    = slot >> 2;
        int blk  = slot & 3;
        gl16(Vt + (size_t)(bD + d)*L_ + k0 + ((blk ^ ((d >> 1) & 3))*8),
             vs + (size_t)(p*512 + w*64)*8);
    }
}

// -------- K2: attention core, counted-vmcnt 2-deep pipeline --------
// 256 blocks x 8 waves; block owns 128 q rows, streams its batch's K/V once.
// Per tile: {vmcnt(N); s_barrier; QK->softmax->PV->E-store; s_barrier; stage(t+2)}
// E-export stores are NEVER drained in-loop (counted inside the vmcnt budget).
__global__ __launch_bounds__(512) void attnpv_kernel(
    const unsigned short* __restrict__ Qb, const unsigned short* __restrict__ Kb,
    const unsigned short* __restrict__ Vt,
    const float* __restrict__ qn, const float* __restrict__ kn,
    const unsigned char* __restrict__ mask,
    unsigned short* __restrict__ Eb,
    float* __restrict__ rowsum, float* __restrict__ att_out)
{
    __shared__ unsigned short Ks[3][32*256];    // 3 x 16 KB
    __shared__ unsigned short Vs[3][256*32];    // 3 x 16 KB
    __shared__ unsigned short Es[8][16*EPAD];   // per-wave E tile (10 KB)
    __shared__ float         knS[L_];           // 8 KB (keeps kn off vmcnt queue)
    __shared__ unsigned char mkS[L_];           // 2 KB

    const int t  = threadIdx.x;
    // XCD-bijective: s&7 = XCD (round-robin dispatch). Each XCD gets 2 batches.
    const int s  = blockIdx.y * 16 + blockIdx.x;
    const int b  = ((s & 7) << 1) | (s >> 7);
    const int q0 = ((s >> 3) & 15) * 128;
    const int bk = b * L_;
    const int bD = b * D_;
    const int w = t >> 6, lane = t & 63, q16 = lane & 15, quad = lane >> 4;
    const int qrow = bk + q0 + w*16;

    // kn/mask -> LDS (coalesced, once)
    *(float4*)&knS[t*4] = *(const float4*)&kn[bk + t*4];
    ((unsigned*)mkS)[t] = ((const unsigned*)(mask + bk))[t];

    s8v qa[8];
    float qnr[4];
    #pragma unroll
    for (int c = 0; c < 8; ++c)
        qa[c] = *(const s8v*)(Qb + (size_t)(qrow + q16)*D_ + c*32 + quad*8);
    #pragma unroll
    for (int r = 0; r < 4; ++r)
        qnr[r] = qn[qrow + quad*4 + r];

    unsigned short* ebase = Eb + (size_t)(qrow + (lane >> 2))*L_ + (lane & 3)*8;
    const unsigned short* esrc = &Es[w][(lane >> 2)*EPAD + (lane & 3)*8];

    float rs[4] = {0.f, 0.f, 0.f, 0.f};
    const f4v z4 = {0.f, 0.f, 0.f, 0.f};
    f4v O[16];
    #pragma unroll
    for (int n = 0; n < 16; ++n) O[n] = z4;

    // one k-tile: QK MFMA -> E -> Es roundtrip -> PV MFMA -> E export (1 store)
    auto do_tile = [&](int kt, int cur) {
        const int k0 = kt * 32;
        float kcv[2]; int mkv[2];
        #pragma unroll
        for (int n = 0; n < 2; ++n) {
            kcv[n] = knS[k0 + n*16 + q16];
            mkv[n] = mkS[k0 + n*16 + q16];
        }
        #pragma unroll
        for (int n = 0; n < 2; ++n) {
            f4v s4 = z4;
            __builtin_amdgcn_s_setprio(1);
            #pragma unroll
            for (int c = 0; c < 8; ++c) {
                s8v bb = *(const s8v*)(Ks[cur] + (n*16 + q16)*256 + (((c*4+quad) ^ q16)*8));
                s4 = __builtin_amdgcn_mfma_f32_16x16x32_bf16(qa[c], bb, s4, 0, 0, 0);
            }
            __builtin_amdgcn_s_setprio(0);
            #pragma unroll
            for (int r = 0; r < 4; ++r) {
                float d2 = fmaf(-2.0f, s4[r], qnr[r] + kcv[n]);
                float dist = sqrtf(fmaxf(d2, 0.f));
                float E = mkv[n] ? 0.f : __expf(__expf(-dist));
                rs[r] += E;
                Es[w][(quad*4 + r)*EPAD + n*16 + q16] = f2b(E);
            }
        }
        s8v af = *(const s8v*)(&Es[w][q16*EPAD + quad*8]);   // same-wave roundtrip
        __builtin_amdgcn_s_setprio(1);
        #pragma unroll
        for (int n = 0; n < 16; ++n) {
            s8v vb = *(const s8v*)(Vs[cur] + (n*16 + q16)*32 +
                                   ((quad ^ ((q16 >> 1) & 3))*8));
            O[n] = __builtin_amdgcn_mfma_f32_16x16x32_bf16(af, vb, O[n], 0, 0, 0);
        }
        __builtin_amdgcn_s_setprio(0);
        *(s8v*)(ebase + k0) = *(const s8v*)esrc;             // 1 vmem store
    };

    // prologue: 2 tiles in flight
    stage_K(Kb, Ks[0], bk, 0,  w, lane);  stage_V(Vt, Vs[0], bD, 0,  w, lane);
    stage_K(Kb, Ks[1], bk, 32, w, lane);  stage_V(Vt, Vs[1], bD, 32, w, lane);

    // iter 0 (peeled): drain stage(0) only (4 newest = stage(1)); lgkm for knS/mkS
    asm volatile("s_waitcnt vmcnt(4) lgkmcnt(0)\n\ts_barrier" ::: "memory");
    do_tile(0, 0);
    asm volatile("s_barrier" ::: "memory");
    stage_K(Kb, Ks[2], bk, 64, w, lane);  stage_V(Vt, Vs[2], bD, 64, w, lane);

    // steady state: allow {stage(t+1):4, store(t-1):1} = 5 outstanding
    int cur = 1;
    for (int kt = 1; kt <= 62; ++kt) {
        asm volatile("s_waitcnt vmcnt(5)\n\ts_barrier" ::: "memory");
        do_tile(kt, cur);
        asm volatile("s_barrier" ::: "memory");
        if (kt <= 61) {
            int nb = cur - 1; if (nb < 0) nb = 2;   // (kt+2) % 3
            stage_K(Kb, Ks[nb], bk, (kt+2)*32, w, lane);
            stage_V(Vt, Vs[nb], bD, (kt+2)*32, w, lane);
        }
        cur = (cur == 2) ? 0 : cur + 1;
    }
    // last iter (peeled): no stage(65) padding the count -> drain to 1 (E-store)
    asm volatile("s_waitcnt vmcnt(1)\n\ts_barrier" ::: "memory");
    do_tile(63, 0);

    // epilogue: rowsum butterfly (intra-wave), att_out NT stores
    float inv4[4];
    #pragma unroll
    for (int r = 0; r < 4; ++r) {
        float v = rs[r];
        v += __shfl_xor(v, 1, 16);
        v += __shfl_xor(v, 2, 16);
        v += __shfl_xor(v, 4, 16);
        v += __shfl_xor(v, 8, 16);
        inv4[r] = 1.0f / v;
        if (q16 == 0) rowsum[qrow + quad*4 + r] = v;
    }
    #pragma unroll
    for (int n = 0; n < 16; ++n)
        #pragma unroll
        for (int r = 0; r < 4; ++r)
            __builtin_nontemporal_store(O[n][r] * inv4[r],
                att_out + (size_t)(qrow + quad*4 + r)*D_ + n*16 + q16);
}

// -------- K3: attn = E * (1/rowsum), pure streaming, full occupancy --------
__global__ __launch_bounds__(256) void norm_kernel(
    const unsigned short* __restrict__ Eb,
    const float* __restrict__ rowsum,
    float* __restrict__ attn_out)
{
    const int row = blockIdx.x;
    const int t   = threadIdx.x;
    const float inv = 1.0f / rowsum[row];
    const size_t base = (size_t)row * L_ + t*8;

    s8v e = *(const s8v*)(Eb + base);
    f4n o0, o1;
    o0.x = __builtin_bit_cast(float, ((unsigned)(unsigned short)e[0]) << 16) * inv;
    o0.y = __builtin_bit_cast(float, ((unsigned)(unsigned short)e[1]) << 16) * inv;
    o0.z = __builtin_bit_cast(float, ((unsigned)(unsigned short)e[2]) << 16) * inv;
    o0.w = __builtin_bit_cast(float, ((unsigned)(unsigned short)e[3]) << 16) * inv;
    o1.x = __builtin_bit_cast(float, ((unsigned)(unsigned short)e[4]) << 16) * inv;
    o1.y = __builtin_bit_cast(float, ((unsigned)(unsigned short)e[5]) << 16) * inv;
    o1.z = __builtin_bit_cast(float, ((unsigned)(unsigned short)e[6]) << 16) * inv;
    o1.w = __builtin_bit_cast(float, ((unsigned)(unsigned short)e[7]) << 16) * inv;
    __builtin_nontemporal_store(o0, (f4n*)(attn_out + base));
    __builtin_nontemporal_store(o1, (f4n*)(attn_out + base + 4));
}

extern "C" void kernel_launch(void* const* d_in, const int* in_sizes, int n_in,
                              void* d_out, int out_size, void* d_ws, size_t ws_size,
                              hipStream_t stream) {
    (void)in_sizes; (void)n_in; (void)out_size; (void)ws_size;
    const float* x  = (const float*)d_in[0];
    const float* y  = (const float*)d_in[1];
    const unsigned char* mask = (const unsigned char*)d_in[2];
    const float* Wq = (const float*)d_in[3];
    const float* Wk = (const float*)d_in[4];
    const float* Wv = (const float*)d_in[5];

    // ws: Qb | Kb | Vt (bf16) | qn | kn | rowsum (fp32) | Eb (bf16, 134 MB)
    char* ws = (char*)d_ws;
    unsigned short* Qb = (unsigned short*)ws;
    unsigned short* Kb = Qb + (size_t)NROW * D_;
    unsigned short* Vt = Kb + (size_t)NROW * D_;
    float* qn     = (float*)(ws + 3 * (size_t)NROW * D_ * 2);
    float* kn     = qn + NROW;
    float* rowsum = kn + NROW;
    unsigned short* Eb = (unsigned short*)(rowsum + NROW);

    float* att_out = (float*)d_out;                       // [B, LQ, D]
    float* attn    = att_out + (size_t)NROW * D_;         // [B, LQ, LK]

    qkv_kernel<<<dim3(512, 2), 256, 0, stream>>>(x, y, Wq, Wk, Wv,
                                                 Qb, Kb, Vt, qn, kn);
    attnpv_kernel<<<dim3(16, 16), 512, 0, stream>>>(Qb, Kb, Vt, qn, kn, mask,
                                                    Eb, rowsum, att_out);
    norm_kernel<<<dim3(NROW), 256, 0, stream>>>(Eb, rowsum, attn);
}

// Round 4
// 567.360 us; speedup vs baseline: 1.0674x; 1.0139x over previous
//
#include <hip/hip_runtime.h>
#include <stdint.h>

#define B_   16
#define L_   2048
#define D_   256
#define NROW (B_*L_)

#define EPAD 40    // Es row stride (shorts)
#define TPAD 66    // qkv transpose buffer row stride

typedef __attribute__((ext_vector_type(8))) short s8v;   // 8 x bf16 (as shorts)
typedef __attribute__((ext_vector_type(4))) float f4v;   // MFMA accumulator
typedef __attribute__((ext_vector_type(4))) float f4n;   // native float4 (NT stores)

__device__ __forceinline__ unsigned short f2b(float f) {   // RNE f32->bf16
    unsigned u = __builtin_bit_cast(unsigned, f);
    return (unsigned short)((u + 0x7fffu + ((u >> 16) & 1u)) >> 16);
}

// HW packed f32->bf16 (RNE): d.lo = bf16(a), d.hi = bf16(b)
__device__ __forceinline__ unsigned cvtpk(float a, float b) {
    unsigned r;
    asm("v_cvt_pk_bf16_f32 %0, %1, %2" : "=v"(r) : "v"(a), "v"(b));
    return r;
}

// async global->LDS, 16B per lane; LDS dest = wave-uniform base + lane*16
__device__ __forceinline__ void gl16(const void* g, void* l) {
    __builtin_amdgcn_global_load_lds(
        (const __attribute__((address_space(1))) unsigned int*)g,
        (__attribute__((address_space(3))) unsigned int*)l, 16, 0, 0);
}

template<int N> __device__ __forceinline__ void waitbar() {
    asm volatile("s_waitcnt vmcnt(%0)\n\ts_barrier" :: "i"(N) : "memory");
}
__device__ __forceinline__ void barOnly() {
    asm volatile("s_barrier" ::: "memory");
}

// -------- K0: pre-convert Wq/Wk/Wv fp32 -> bf16, pre-swizzled for gl16 ------
// Wb layout: [3][256 rows e][32 chunks of 16B], chunk at pos (blk ^ (e&15)).
__global__ __launch_bounds__(256) void wconv_kernel(
    const float* __restrict__ Wq, const float* __restrict__ Wk,
    const float* __restrict__ Wv, unsigned short* __restrict__ Wb)
{
    const int t  = threadIdx.x;
    const int r0 = blockIdx.x * 64;
    const int wt = blockIdx.y;
    const float* W = wt == 0 ? Wq : (wt == 1 ? Wk : Wv);
    unsigned short* O = Wb + (size_t)wt * 256 * 256;
    #pragma unroll
    for (int p = 0; p < 16; ++p) {
        int idx  = p*256 + t;
        int row  = r0 + (idx >> 6);
        int half = idx & 1;
        int blk  = (idx & 63) >> 1;
        int c4   = blk*8 + half*4;
        float4 v = *(const float4*)(W + (size_t)row*D_ + c4);
        uint2 pw; pw.x = cvtpk(v.x, v.y); pw.y = cvtpk(v.z, v.w);
        *(uint2*)(O + row*256 + (blk ^ (row & 15))*8 + half*4) = pw;
    }
}

// weight half-tile (32 rows x 256 cols bf16, 16 KB) -> LDS via DMA (linear copy,
// swizzle already applied in Wb). 4 chunks per thread.
__device__ __forceinline__ void stage_W(const unsigned short* Wsrc, unsigned short* buf,
                                        int e0h, int w, int lane) {
    #pragma unroll
    for (int p = 0; p < 4; ++p) {
        int slot = p*256 + w*64 + lane;
        int row  = slot >> 5;      // 0..31
        int blk  = slot & 31;
        gl16(Wsrc + (size_t)(e0h + row)*256 + blk*8,
             buf + (size_t)(p*256 + w*64)*8);
    }
}

// ---------------- K1: QKV projection (pipelined weight DMA) ----------------
// grid (512 row-blocks, 2 types), block 256 (4 waves), 2 blocks/CU.
// type0: Q (8 half-phases).  type1: K then V (16 half-phases), y staged once.
// Per phase: {counted vmcnt; barrier; 16 MFMA (+epilogue on odd); barrier;
//             DMA-prefetch half-tile h+2}.  Weight stores never VALU-converted.
__global__ __launch_bounds__(256) void qkv_kernel(
    const float* __restrict__ x, const float* __restrict__ y,
    const unsigned short* __restrict__ Wb,
    unsigned short* __restrict__ Qb, unsigned short* __restrict__ Kb,
    unsigned short* __restrict__ Vt,
    float* __restrict__ qn, float* __restrict__ kn)
{
    __shared__ unsigned short Xs[64*256];      // 32 KB input tile (bf16)
    __shared__ unsigned short Wsb[2][32*256];  // 2 x 16 KB weight half-tiles
    __shared__ unsigned short Ts[64*TPAD];     // V transpose buffer (8.4 KB)

    const int t    = threadIdx.x;
    const int r0   = blockIdx.x * 64;   // global row (flat b*L + pos)
    const int type = blockIdx.y;        // 0=Q  1=K+V
    const float* X = type ? y : x;

    // Stage X tile [64][256] fp32 -> bf16 LDS, 16B-chunk swizzled by row&15.
    #pragma unroll
    for (int p = 0; p < 16; ++p) {
        int idx  = p*256 + t;
        int row  = idx >> 6;
        int half = idx & 1;
        int blk  = (idx & 63) >> 1;
        int c4   = blk*8 + half*4;
        float4 vx = *(const float4*)(X + (size_t)(r0+row)*D_ + c4);
        uint2 px; px.x = cvtpk(vx.x, vx.y); px.y = cvtpk(vx.z, vx.w);
        *(uint2*)(Xs + row*256 + (blk ^ (row & 15))*8 + half*4) = px;
    }

    const int w = t >> 6, lane = t & 63, q16 = lane & 15, quad = lane >> 4;
    const int m0 = w * 16;

    const unsigned short* W0 = Wb + (type ? 65536 : 0);   // Wq or Wk
    const unsigned short* W1 = Wb + 131072;               // Wv

    stage_W(W0, Wsb[0], 0,  w, lane);   // H0
    stage_W(W0, Wsb[1], 32, w, lane);   // H1

    // phase 0 entry: drain H0 (keep H1), Xs ds-writes visible
    asm volatile("s_waitcnt vmcnt(4) lgkmcnt(0)\n\ts_barrier" ::: "memory");

    // hoist A-fragments (reused in every phase)
    s8v xa[8];
    #pragma unroll
    for (int c = 0; c < 8; ++c)
        xa[c] = *(const s8v*)(Xs + (m0 + q16)*256 + (((c*4+quad) ^ q16)*8));

    float p4[4] = {0.f, 0.f, 0.f, 0.f};
    const f4v z4 = {0.f, 0.f, 0.f, 0.f};
    f4v acc[4];

    auto compute_half = [&](int par) {   // fills acc[par*2 + nn] from Wsb[par]
        #pragma unroll
        for (int c = 0; c < 8; ++c)
            #pragma unroll
            for (int nn = 0; nn < 2; ++nn) {
                s8v bb = *(const s8v*)(Wsb[par] + (nn*16 + q16)*256 + (((c*4+quad) ^ q16)*8));
                acc[par*2+nn] = __builtin_amdgcn_mfma_f32_16x16x32_bf16(xa[c], bb, acc[par*2+nn], 0, 0, 0);
            }
    };

    auto epi_qk = [&](int ct) {          // 16 b16 stores
        unsigned short* Out = type ? Kb : Qb;
        #pragma unroll
        for (int n = 0; n < 4; ++n)
            #pragma unroll
            for (int r = 0; r < 4; ++r) {
                float v = acc[n][r];
                p4[r] += v * v;
                Out[(size_t)(r0 + m0 + quad*4 + r)*D_ + ct*64 + n*16 + q16] = f2b(v);
            }
    };

    auto epi_v = [&](int ct) {           // transpose via Ts, 2 dwordx4 stores
        #pragma unroll
        for (int n = 0; n < 4; ++n)
            #pragma unroll
            for (int r = 0; r < 4; ++r)
                Ts[(m0 + quad*4 + r)*TPAD + n*16 + q16] = f2b(acc[n][r]);
        asm volatile("s_waitcnt lgkmcnt(0)\n\ts_barrier" ::: "memory");
        int j = t >> 2, kseg = t & 3;
        unsigned pk[8];
        #pragma unroll
        for (int i = 0; i < 8; ++i) {
            unsigned lo = Ts[(kseg*16 + 2*i    )*TPAD + j];
            unsigned hi = Ts[(kseg*16 + 2*i + 1)*TPAD + j];
            pk[i] = lo | (hi << 16);
        }
        int bb_ = r0 >> 11, k0g = r0 & (L_ - 1);
        unsigned short* dst = Vt + (size_t)(bb_*D_ + ct*64 + j)*L_ + k0g + kseg*16;
        *(uint4*)dst       = make_uint4(pk[0], pk[1], pk[2], pk[3]);
        *((uint4*)dst + 1) = make_uint4(pk[4], pk[5], pk[6], pk[7]);
    };

    if (!type) {
        // 8 phases: Wq halves H0..H7.  Epi (16 stores) after odd phases.
        #pragma unroll
        for (int h = 0; h < 8; ++h) {
            if (h == 7)      waitbar<0>();
            else if (h > 0) { if (h & 1) waitbar<4>(); else waitbar<20>(); }
            const int par = h & 1;
            acc[par*2] = z4; acc[par*2+1] = z4;
            compute_half(par);
            if (par) epi_qk(h >> 1);
            barOnly();
            if (h + 2 < 8) stage_W(W0, Wsb[par], (h+2)*32, w, lane);
        }
    } else {
        // 16 phases: Wk H0..H7 then Wv H0..H7.
        // K-epi (16 stores) after 1,3,5,7; V-epi (2 stores) after 9,11,13,15.
        #pragma unroll
        for (int h = 0; h < 16; ++h) {
            if (h == 15)     waitbar<0>();
            else if (h > 0) {
                if (h & 1)       waitbar<4>();
                else if (h <= 8) waitbar<20>();
                else             waitbar<6>();
            }
            const int par = h & 1;
            acc[par*2] = z4; acc[par*2+1] = z4;
            compute_half(par);
            if (par) { if (h < 8) epi_qk(h >> 1); else epi_v((h - 8) >> 1); }
            barOnly();
            if (h + 2 < 16) {
                const unsigned short* Ws_ = (h + 2 < 8) ? W0 : W1;
                stage_W(Ws_, Wsb[par], ((h + 2) & 7) * 32, w, lane);
            }
        }
    }

    {
        float* norm = type ? kn : qn;
        #pragma unroll
        for (int r = 0; r < 4; ++r) {
            float v = p4[r];
            v += __shfl_xor(v, 1, 16);
            v += __shfl_xor(v, 2, 16);
            v += __shfl_xor(v, 4, 16);
            v += __shfl_xor(v, 8, 16);
            if (q16 == 0) norm[r0 + m0 + quad*4 + r] = v;
        }
    }
}

// ---- staging helpers for 8-wave (512 thr) blocks ----
// Ks tile: 32 rows x 256 cols bf16 (16 KB) = 1024 x 16B chunks, 2 per lane
__device__ __forceinline__ void stage_K(const unsigned short* Kb, unsigned short* ks,
                                        int bk, int k0, int w, int lane) {
    #pragma unroll
    for (int p = 0; p < 2; ++p) {
        int slot = p*512 + w*64 + lane;
        int row  = slot >> 5;
        int blk  = slot & 31;
        gl16(Kb + (size_t)(bk + k0 + row)*D_ + ((blk ^ (row & 15))*8),
             ks + (size_t)(p*512 + w*64)*8);
    }
}
// Vs tile: 256 rows(d) x 32 cols(k) bf16 (16 KB)
__device__ __forceinline__ void stage_V(const unsigned short* Vt, unsigned short* vs,
                                        int bD, int k0, int w, int lane) {
    #pragma unroll
    for (int p = 0; p < 2; ++p) {
        int slot = p*512 + w*64 + lane;
        int d    = slot >> 2;
        int blk  = slot & 3;
        gl16(Vt + (size_t)(bD + d)*L_ + k0 + ((blk ^ ((d >> 1) & 3))*8),
             vs + (size_t)(p*512 + w*64)*8);
    }
}

// -------- K2: attention core, counted-vmcnt 2-deep pipeline --------
__global__ __launch_bounds__(512) void attnpv_kernel(
    const unsigned short* __restrict__ Qb, const unsigned short* __restrict__ Kb,
    const unsigned short* __restrict__ Vt,
    const float* __restrict__ qn, const float* __restrict__ kn,
    const unsigned char* __restrict__ mask,
    unsigned short* __restrict__ Eb,
    float* __restrict__ rowsum, float* __restrict__ att_out)
{
    __shared__ unsigned short Ks[3][32*256];    // 3 x 16 KB
    __shared__ unsigned short Vs[3][256*32];    // 3 x 16 KB
    __shared__ unsigned short Es[8][16*EPAD];   // per-wave E tile (10 KB)
    __shared__ float         knS[L_];           // 8 KB
    __shared__ unsigned char mkS[L_];           // 2 KB

    const int t  = threadIdx.x;
    const int s  = blockIdx.y * 16 + blockIdx.x;
    const int b  = ((s & 7) << 1) | (s >> 7);
    const int q0 = ((s >> 3) & 15) * 128;
    const int bk = b * L_;
    const int bD = b * D_;
    const int w = t >> 6, lane = t & 63, q16 = lane & 15, quad = lane >> 4;
    const int qrow = bk + q0 + w*16;

    *(float4*)&knS[t*4] = *(const float4*)&kn[bk + t*4];
    ((unsigned*)mkS)[t] = ((const unsigned*)(mask + bk))[t];

    s8v qa[8];
    float qnr[4];
    #pragma unroll
    for (int c = 0; c < 8; ++c)
        qa[c] = *(const s8v*)(Qb + (size_t)(qrow + q16)*D_ + c*32 + quad*8);
    #pragma unroll
    for (int r = 0; r < 4; ++r)
        qnr[r] = qn[qrow + quad*4 + r];

    unsigned short* ebase = Eb + (size_t)(qrow + (lane >> 2))*L_ + (lane & 3)*8;
    const unsigned short* esrc = &Es[w][(lane >> 2)*EPAD + (lane & 3)*8];

    float rs[4] = {0.f, 0.f, 0.f, 0.f};
    const f4v z4 = {0.f, 0.f, 0.f, 0.f};
    f4v O[16];
    #pragma unroll
    for (int n = 0; n < 16; ++n) O[n] = z4;

    auto do_tile = [&](int kt, int cur) {
        const int k0 = kt * 32;
        float kcv[2]; int mkv[2];
        #pragma unroll
        for (int n = 0; n < 2; ++n) {
            kcv[n] = knS[k0 + n*16 + q16];
            mkv[n] = mkS[k0 + n*16 + q16];
        }
        #pragma unroll
        for (int n = 0; n < 2; ++n) {
            f4v s4 = z4;
            __builtin_amdgcn_s_setprio(1);
            #pragma unroll
            for (int c = 0; c < 8; ++c) {
                s8v bb = *(const s8v*)(Ks[cur] + (n*16 + q16)*256 + (((c*4+quad) ^ q16)*8));
                s4 = __builtin_amdgcn_mfma_f32_16x16x32_bf16(qa[c], bb, s4, 0, 0, 0);
            }
            __builtin_amdgcn_s_setprio(0);
            #pragma unroll
            for (int r = 0; r < 4; ++r) {
                float d2 = fmaf(-2.0f, s4[r], qnr[r] + kcv[n]);
                float dist = sqrtf(fmaxf(d2, 0.f));
                float E = mkv[n] ? 0.f : __expf(__expf(-dist));
                rs[r] += E;
                Es[w][(quad*4 + r)*EPAD + n*16 + q16] = f2b(E);
            }
        }
        // E export issued BEFORE PV: store overlaps the 16 PV MFMAs
        *(s8v*)(ebase + k0) = *(const s8v*)esrc;
        s8v af = *(const s8v*)(&Es[w][q16*EPAD + quad*8]);
        __builtin_amdgcn_s_setprio(1);
        #pragma unroll
        for (int n = 0; n < 16; ++n) {
            s8v vb = *(const s8v*)(Vs[cur] + (n*16 + q16)*32 +
                                   ((quad ^ ((q16 >> 1) & 3))*8));
            O[n] = __builtin_amdgcn_mfma_f32_16x16x32_bf16(af, vb, O[n], 0, 0, 0);
        }
        __builtin_amdgcn_s_setprio(0);
    };

    stage_K(Kb, Ks[0], bk, 0,  w, lane);  stage_V(Vt, Vs[0], bD, 0,  w, lane);
    stage_K(Kb, Ks[1], bk, 32, w, lane);  stage_V(Vt, Vs[1], bD, 32, w, lane);

    asm volatile("s_waitcnt vmcnt(4) lgkmcnt(0)\n\ts_barrier" ::: "memory");
    do_tile(0, 0);
    asm volatile("s_barrier" ::: "memory");
    stage_K(Kb, Ks[2], bk, 64, w, lane);  stage_V(Vt, Vs[2], bD, 64, w, lane);

    int cur = 1;
    for (int kt = 1; kt <= 62; ++kt) {
        asm volatile("s_waitcnt vmcnt(5)\n\ts_barrier" ::: "memory");
        do_tile(kt, cur);
        asm volatile("s_barrier" ::: "memory");
        if (kt <= 61) {
            int nb = cur - 1; if (nb < 0) nb = 2;
            stage_K(Kb, Ks[nb], bk, (kt+2)*32, w, lane);
            stage_V(Vt, Vs[nb], bD, (kt+2)*32, w, lane);
        }
        cur = (cur == 2) ? 0 : cur + 1;
    }
    asm volatile("s_waitcnt vmcnt(1)\n\ts_barrier" ::: "memory");
    do_tile(63, 0);

    float inv4[4];
    #pragma unroll
    for (int r = 0; r < 4; ++r) {
        float v = rs[r];
        v += __shfl_xor(v, 1, 16);
        v += __shfl_xor(v, 2, 16);
        v += __shfl_xor(v, 4, 16);
        v += __shfl_xor(v, 8, 16);
        inv4[r] = 1.0f / v;
        if (q16 == 0) rowsum[qrow + quad*4 + r] = v;
    }
    #pragma unroll
    for (int n = 0; n < 16; ++n)
        #pragma unroll
        for (int r = 0; r < 4; ++r)
            __builtin_nontemporal_store(O[n][r] * inv4[r],
                att_out + (size_t)(qrow + quad*4 + r)*D_ + n*16 + q16);
}

// -------- K3: attn = E * (1/rowsum), pure streaming, full occupancy --------
__global__ __launch_bounds__(256) void norm_kernel(
    const unsigned short* __restrict__ Eb,
    const float* __restrict__ rowsum,
    float* __restrict__ attn_out)
{
    const int row = blockIdx.x;
    const int t   = threadIdx.x;
    const float inv = 1.0f / rowsum[row];
    const size_t base = (size_t)row * L_ + t*8;

    s8v e = *(const s8v*)(Eb + base);
    f4n o0, o1;
    o0.x = __builtin_bit_cast(float, ((unsigned)(unsigned short)e[0]) << 16) * inv;
    o0.y = __builtin_bit_cast(float, ((unsigned)(unsigned short)e[1]) << 16) * inv;
    o0.z = __builtin_bit_cast(float, ((unsigned)(unsigned short)e[2]) << 16) * inv;
    o0.w = __builtin_bit_cast(float, ((unsigned)(unsigned short)e[3]) << 16) * inv;
    o1.x = __builtin_bit_cast(float, ((unsigned)(unsigned short)e[4]) << 16) * inv;
    o1.y = __builtin_bit_cast(float, ((unsigned)(unsigned short)e[5]) << 16) * inv;
    o1.z = __builtin_bit_cast(float, ((unsigned)(unsigned short)e[6]) << 16) * inv;
    o1.w = __builtin_bit_cast(float, ((unsigned)(unsigned short)e[7]) << 16) * inv;
    __builtin_nontemporal_store(o0, (f4n*)(attn_out + base));
    __builtin_nontemporal_store(o1, (f4n*)(attn_out + base + 4));
}

extern "C" void kernel_launch(void* const* d_in, const int* in_sizes, int n_in,
                              void* d_out, int out_size, void* d_ws, size_t ws_size,
                              hipStream_t stream) {
    (void)in_sizes; (void)n_in; (void)out_size; (void)ws_size;
    const float* x  = (const float*)d_in[0];
    const float* y  = (const float*)d_in[1];
    const unsigned char* mask = (const unsigned char*)d_in[2];
    const float* Wq = (const float*)d_in[3];
    const float* Wk = (const float*)d_in[4];
    const float* Wv = (const float*)d_in[5];

    // ws: Qb | Kb | Vt (bf16) | qn | kn | rowsum (fp32) | Eb (bf16) | Wb (bf16)
    char* ws = (char*)d_ws;
    unsigned short* Qb = (unsigned short*)ws;
    unsigned short* Kb = Qb + (size_t)NROW * D_;
    unsigned short* Vt = Kb + (size_t)NROW * D_;
    float* qn     = (float*)(ws + 3 * (size_t)NROW * D_ * 2);
    float* kn     = qn + NROW;
    float* rowsum = kn + NROW;
    unsigned short* Eb = (unsigned short*)(rowsum + NROW);
    unsigned short* Wb = Eb + (size_t)NROW * L_;

    float* att_out = (float*)d_out;                       // [B, LQ, D]
    float* attn    = att_out + (size_t)NROW * D_;         // [B, LQ, LK]

    wconv_kernel<<<dim3(4, 3), 256, 0, stream>>>(Wq, Wk, Wv, Wb);
    qkv_kernel<<<dim3(512, 2), 256, 0, stream>>>(x, y, Wb, Qb, Kb, Vt, qn, kn);
    attnpv_kernel<<<dim3(16, 16), 512, 0, stream>>>(Qb, Kb, Vt, qn, kn, mask,
                                                    Eb, rowsum, att_out);
    norm_kernel<<<dim3(NROW), 256, 0, stream>>>(Eb, rowsum, attn);
}

// Round 5
// 564.307 us; speedup vs baseline: 1.0731x; 1.0054x over previous
//
#include <hip/hip_runtime.h>
#include <stdint.h>

#define B_   16
#define L_   2048
#define D_   256
#define NROW (B_*L_)

#define EPAD 40    // Es row stride (shorts)
#define TPAD 66    // qkv transpose buffer row stride

typedef __attribute__((ext_vector_type(8))) short s8v;   // 8 x bf16 (as shorts)
typedef __attribute__((ext_vector_type(4))) float f4v;   // MFMA accumulator
typedef __attribute__((ext_vector_type(4))) float f4n;   // native float4 (NT stores)

__device__ __forceinline__ unsigned short f2b(float f) {   // RNE f32->bf16
    unsigned u = __builtin_bit_cast(unsigned, f);
    return (unsigned short)((u + 0x7fffu + ((u >> 16) & 1u)) >> 16);
}

// HW packed f32->bf16 (RNE): d.lo = bf16(a), d.hi = bf16(b)
__device__ __forceinline__ unsigned cvtpk(float a, float b) {
    unsigned r;
    asm("v_cvt_pk_bf16_f32 %0, %1, %2" : "=v"(r) : "v"(a), "v"(b));
    return r;
}

// async global->LDS, 16B per lane; LDS dest = wave-uniform base + lane*16
__device__ __forceinline__ void gl16(const void* g, void* l) {
    __builtin_amdgcn_global_load_lds(
        (const __attribute__((address_space(1))) unsigned int*)g,
        (__attribute__((address_space(3))) unsigned int*)l, 16, 0, 0);
}

template<int N> __device__ __forceinline__ void waitbar() {
    asm volatile("s_waitcnt vmcnt(%0)\n\ts_barrier" :: "i"(N) : "memory");
}
__device__ __forceinline__ void barOnly() {
    asm volatile("s_barrier" ::: "memory");
}

// -------- K0: pre-convert Wq/Wk/Wv fp32 -> bf16, pre-swizzled for gl16 ------
// Wb layout: [3][256 rows e][32 chunks of 16B], chunk at pos (blk ^ (e&15)).
__global__ __launch_bounds__(256) void wconv_kernel(
    const float* __restrict__ Wq, const float* __restrict__ Wk,
    const float* __restrict__ Wv, unsigned short* __restrict__ Wb)
{
    const int t  = threadIdx.x;
    const int r0 = blockIdx.x * 64;
    const int wt = blockIdx.y;
    const float* W = wt == 0 ? Wq : (wt == 1 ? Wk : Wv);
    unsigned short* O = Wb + (size_t)wt * 256 * 256;
    #pragma unroll
    for (int p = 0; p < 16; ++p) {
        int idx  = p*256 + t;
        int row  = r0 + (idx >> 6);
        int half = idx & 1;
        int blk  = (idx & 63) >> 1;
        int c4   = blk*8 + half*4;
        float4 v = *(const float4*)(W + (size_t)row*D_ + c4);
        uint2 pw; pw.x = cvtpk(v.x, v.y); pw.y = cvtpk(v.z, v.w);
        *(uint2*)(O + row*256 + (blk ^ (row & 15))*8 + half*4) = pw;
    }
}

// weight half-tile (32 rows x 256 cols bf16, 16 KB) -> LDS via DMA (linear copy,
// swizzle already applied in Wb). 4 chunks per thread.
__device__ __forceinline__ void stage_W(const unsigned short* Wsrc, unsigned short* buf,
                                        int e0h, int w, int lane) {
    #pragma unroll
    for (int p = 0; p < 4; ++p) {
        int slot = p*256 + w*64 + lane;
        int row  = slot >> 5;      // 0..31
        int blk  = slot & 31;
        gl16(Wsrc + (size_t)(e0h + row)*256 + blk*8,
             buf + (size_t)(p*256 + w*64)*8);
    }
}

// ---------------- K1: QKV projection (pipelined weight DMA) ----------------
__global__ __launch_bounds__(256) void qkv_kernel(
    const float* __restrict__ x, const float* __restrict__ y,
    const unsigned short* __restrict__ Wb,
    unsigned short* __restrict__ Qb, unsigned short* __restrict__ Kb,
    unsigned short* __restrict__ Vt,
    float* __restrict__ qn, float* __restrict__ kn)
{
    __shared__ unsigned short Xs[64*256];      // 32 KB input tile (bf16)
    __shared__ unsigned short Wsb[2][32*256];  // 2 x 16 KB weight half-tiles
    __shared__ unsigned short Ts[64*TPAD];     // V transpose buffer (8.4 KB)

    const int t    = threadIdx.x;
    const int r0   = blockIdx.x * 64;   // global row (flat b*L + pos)
    const int type = blockIdx.y;        // 0=Q  1=K+V
    const float* X = type ? y : x;

    // Stage X tile [64][256] fp32 -> bf16 LDS, 16B-chunk swizzled by row&15.
    #pragma unroll
    for (int p = 0; p < 16; ++p) {
        int idx  = p*256 + t;
        int row  = idx >> 6;
        int half = idx & 1;
        int blk  = (idx & 63) >> 1;
        int c4   = blk*8 + half*4;
        float4 vx = *(const float4*)(X + (size_t)(r0+row)*D_ + c4);
        uint2 px; px.x = cvtpk(vx.x, vx.y); px.y = cvtpk(vx.z, vx.w);
        *(uint2*)(Xs + row*256 + (blk ^ (row & 15))*8 + half*4) = px;
    }

    const int w = t >> 6, lane = t & 63, q16 = lane & 15, quad = lane >> 4;
    const int m0 = w * 16;

    const unsigned short* W0 = Wb + (type ? 65536 : 0);   // Wq or Wk
    const unsigned short* W1 = Wb + 131072;               // Wv

    stage_W(W0, Wsb[0], 0,  w, lane);   // H0
    stage_W(W0, Wsb[1], 32, w, lane);   // H1

    // phase 0 entry: drain H0 (keep H1), Xs ds-writes visible
    asm volatile("s_waitcnt vmcnt(4) lgkmcnt(0)\n\ts_barrier" ::: "memory");

    // hoist A-fragments (reused in every phase)
    s8v xa[8];
    #pragma unroll
    for (int c = 0; c < 8; ++c)
        xa[c] = *(const s8v*)(Xs + (m0 + q16)*256 + (((c*4+quad) ^ q16)*8));

    float p4[4] = {0.f, 0.f, 0.f, 0.f};
    const f4v z4 = {0.f, 0.f, 0.f, 0.f};
    f4v acc[4];

    auto compute_half = [&](int par) {   // fills acc[par*2 + nn] from Wsb[par]
        #pragma unroll
        for (int c = 0; c < 8; ++c)
            #pragma unroll
            for (int nn = 0; nn < 2; ++nn) {
                s8v bb = *(const s8v*)(Wsb[par] + (nn*16 + q16)*256 + (((c*4+quad) ^ q16)*8));
                acc[par*2+nn] = __builtin_amdgcn_mfma_f32_16x16x32_bf16(xa[c], bb, acc[par*2+nn], 0, 0, 0);
            }
    };

    auto epi_qk = [&](int ct) {          // 16 b16 stores
        unsigned short* Out = type ? Kb : Qb;
        #pragma unroll
        for (int n = 0; n < 4; ++n)
            #pragma unroll
            for (int r = 0; r < 4; ++r) {
                float v = acc[n][r];
                p4[r] += v * v;
                Out[(size_t)(r0 + m0 + quad*4 + r)*D_ + ct*64 + n*16 + q16] = f2b(v);
            }
    };

    auto epi_v = [&](int ct) {           // transpose via Ts, 2 dwordx4 stores
        #pragma unroll
        for (int n = 0; n < 4; ++n)
            #pragma unroll
            for (int r = 0; r < 4; ++r)
                Ts[(m0 + quad*4 + r)*TPAD + n*16 + q16] = f2b(acc[n][r]);
        asm volatile("s_waitcnt lgkmcnt(0)\n\ts_barrier" ::: "memory");
        int j = t >> 2, kseg = t & 3;
        unsigned pk[8];
        #pragma unroll
        for (int i = 0; i < 8; ++i) {
            unsigned lo = Ts[(kseg*16 + 2*i    )*TPAD + j];
            unsigned hi = Ts[(kseg*16 + 2*i + 1)*TPAD + j];
            pk[i] = lo | (hi << 16);
        }
        int bb_ = r0 >> 11, k0g = r0 & (L_ - 1);
        unsigned short* dst = Vt + (size_t)(bb_*D_ + ct*64 + j)*L_ + k0g + kseg*16;
        *(uint4*)dst       = make_uint4(pk[0], pk[1], pk[2], pk[3]);
        *((uint4*)dst + 1) = make_uint4(pk[4], pk[5], pk[6], pk[7]);
    };

    if (!type) {
        // 8 phases: Wq halves H0..H7.  Epi (16 stores) after odd phases.
        #pragma unroll
        for (int h = 0; h < 8; ++h) {
            if (h == 7)      waitbar<0>();
            else if (h > 0) { if (h & 1) waitbar<4>(); else waitbar<20>(); }
            const int par = h & 1;
            acc[par*2] = z4; acc[par*2+1] = z4;
            compute_half(par);
            if (par) epi_qk(h >> 1);
            barOnly();
            if (h + 2 < 8) stage_W(W0, Wsb[par], (h+2)*32, w, lane);
        }
    } else {
        // 16 phases: Wk H0..H7 then Wv H0..H7.
        #pragma unroll
        for (int h = 0; h < 16; ++h) {
            if (h == 15)     waitbar<0>();
            else if (h > 0) {
                if (h & 1)       waitbar<4>();
                else if (h <= 8) waitbar<20>();
                else             waitbar<6>();
            }
            const int par = h & 1;
            acc[par*2] = z4; acc[par*2+1] = z4;
            compute_half(par);
            if (par) { if (h < 8) epi_qk(h >> 1); else epi_v((h - 8) >> 1); }
            barOnly();
            if (h + 2 < 16) {
                const unsigned short* Ws_ = (h + 2 < 8) ? W0 : W1;
                stage_W(Ws_, Wsb[par], ((h + 2) & 7) * 32, w, lane);
            }
        }
    }

    {
        float* norm = type ? kn : qn;
        #pragma unroll
        for (int r = 0; r < 4; ++r) {
            float v = p4[r];
            v += __shfl_xor(v, 1, 16);
            v += __shfl_xor(v, 2, 16);
            v += __shfl_xor(v, 4, 16);
            v += __shfl_xor(v, 8, 16);
            if (q16 == 0) norm[r0 + m0 + quad*4 + r] = v;
        }
    }
}

// ---- staging helpers for 8-wave (512 thr) blocks ----
__device__ __forceinline__ void stage_K(const unsigned short* Kb, unsigned short* ks,
                                        int bk, int k0, int w, int lane) {
    #pragma unroll
    for (int p = 0; p < 2; ++p) {
        int slot = p*512 + w*64 + lane;
        int row  = slot >> 5;
        int blk  = slot & 31;
        gl16(Kb + (size_t)(bk + k0 + row)*D_ + ((blk ^ (row & 15))*8),
             ks + (size_t)(p*512 + w*64)*8);
    }
}
__device__ __forceinline__ void stage_V(const unsigned short* Vt, unsigned short* vs,
                                        int bD, int k0, int w, int lane) {
    #pragma unroll
    for (int p = 0; p < 2; ++p) {
        int slot = p*512 + w*64 + lane;
        int d    = slot >> 2;
        int blk  = slot & 3;
        gl16(Vt + (size_t)(bD + d)*L_ + k0 + ((blk ^ ((d >> 1) & 3))*8),
             vs + (size_t)(p*512 + w*64)*8);
    }
}

// -------- K2: attention core — single barrier/tile, 4-chain QK ILP --------
// 256 blocks x 8 waves; block owns 128 q rows, streams its batch's K/V once.
// Per tile: {vmcnt(5); s_barrier; stage(t+2); QK(4 indep chains)->softmax->
//            NT E-export->PV}.  Second barrier removed: buffer overwritten by
// stage(t+2) was last read at tile t-1, which precedes this tile's barrier.
__global__ __launch_bounds__(512) void attnpv_kernel(
    const unsigned short* __restrict__ Qb, const unsigned short* __restrict__ Kb,
    const unsigned short* __restrict__ Vt,
    const float* __restrict__ qn, const float* __restrict__ kn,
    const unsigned char* __restrict__ mask,
    unsigned short* __restrict__ Eb,
    float* __restrict__ rowsum, float* __restrict__ att_out)
{
    __shared__ unsigned short Ks[3][32*256];    // 3 x 16 KB
    __shared__ unsigned short Vs[3][256*32];    // 3 x 16 KB
    __shared__ unsigned short Es[8][16*EPAD];   // per-wave E tile (10 KB)
    __shared__ float         knS[L_];           // 8 KB
    __shared__ unsigned char mkS[L_];           // 2 KB

    const int t  = threadIdx.x;
    const int s  = blockIdx.y * 16 + blockIdx.x;
    const int b  = ((s & 7) << 1) | (s >> 7);
    const int q0 = ((s >> 3) & 15) * 128;
    const int bk = b * L_;
    const int bD = b * D_;
    const int w = t >> 6, lane = t & 63, q16 = lane & 15, quad = lane >> 4;
    const int qrow = bk + q0 + w*16;

    *(float4*)&knS[t*4] = *(const float4*)&kn[bk + t*4];
    ((unsigned*)mkS)[t] = ((const unsigned*)(mask + bk))[t];

    s8v qa[8];
    float qnr[4];
    #pragma unroll
    for (int c = 0; c < 8; ++c)
        qa[c] = *(const s8v*)(Qb + (size_t)(qrow + q16)*D_ + c*32 + quad*8);
    #pragma unroll
    for (int r = 0; r < 4; ++r)
        qnr[r] = qn[qrow + quad*4 + r];

    unsigned short* ebase = Eb + (size_t)(qrow + (lane >> 2))*L_ + (lane & 3)*8;
    const unsigned short* esrc = &Es[w][(lane >> 2)*EPAD + (lane & 3)*8];

    float rs[4] = {0.f, 0.f, 0.f, 0.f};
    const f4v z4 = {0.f, 0.f, 0.f, 0.f};
    f4v O[16];
    #pragma unroll
    for (int n = 0; n < 16; ++n) O[n] = z4;

    auto do_tile = [&](int k0, const unsigned short* ksb, const unsigned short* vsb) {
        float kcv[2]; int mkv[2];
        #pragma unroll
        for (int n = 0; n < 2; ++n) {
            kcv[n] = knS[k0 + n*16 + q16];
            mkv[n] = mkS[k0 + n*16 + q16];
        }
        // QK: 4 independent MFMA chains (n0/n1 x k-halves), dep distance 4
        f4v sA0 = z4, sA1 = z4, sB0 = z4, sB1 = z4;
        __builtin_amdgcn_s_setprio(1);
        #pragma unroll
        for (int c = 0; c < 4; ++c) {
            const int c0 = 2*c, c1 = 2*c + 1;
            s8v bA0 = *(const s8v*)(ksb + (q16      )*256 + (((c0*4+quad) ^ q16)*8));
            s8v bA1 = *(const s8v*)(ksb + (16 + q16 )*256 + (((c0*4+quad) ^ q16)*8));
            s8v bB0 = *(const s8v*)(ksb + (q16      )*256 + (((c1*4+quad) ^ q16)*8));
            s8v bB1 = *(const s8v*)(ksb + (16 + q16 )*256 + (((c1*4+quad) ^ q16)*8));
            sA0 = __builtin_amdgcn_mfma_f32_16x16x32_bf16(qa[c0], bA0, sA0, 0, 0, 0);
            sA1 = __builtin_amdgcn_mfma_f32_16x16x32_bf16(qa[c0], bA1, sA1, 0, 0, 0);
            sB0 = __builtin_amdgcn_mfma_f32_16x16x32_bf16(qa[c1], bB0, sB0, 0, 0, 0);
            sB1 = __builtin_amdgcn_mfma_f32_16x16x32_bf16(qa[c1], bB1, sB1, 0, 0, 0);
        }
        __builtin_amdgcn_s_setprio(0);
        f4v s4n[2];
        s4n[0] = sA0 + sB0;
        s4n[1] = sA1 + sB1;
        #pragma unroll
        for (int n = 0; n < 2; ++n)
            #pragma unroll
            for (int r = 0; r < 4; ++r) {
                float d2 = fmaf(-2.0f, s4n[n][r], qnr[r] + kcv[n]);
                float dist = sqrtf(fmaxf(d2, 0.f));
                float E = mkv[n] ? 0.f : __expf(__expf(-dist));
                rs[r] += E;
                Es[w][(quad*4 + r)*EPAD + n*16 + q16] = f2b(E);
            }
        // NT E-export issued BEFORE PV (overlaps 16 MFMAs; keeps K/V in L2)
        __builtin_nontemporal_store(*(const s8v*)esrc, (s8v*)(ebase + k0));
        s8v af = *(const s8v*)(&Es[w][q16*EPAD + quad*8]);
        __builtin_amdgcn_s_setprio(1);
        #pragma unroll
        for (int n = 0; n < 16; ++n) {
            s8v vb = *(const s8v*)(vsb + (n*16 + q16)*32 +
                                   ((quad ^ ((q16 >> 1) & 3))*8));
            O[n] = __builtin_amdgcn_mfma_f32_16x16x32_bf16(af, vb, O[n], 0, 0, 0);
        }
        __builtin_amdgcn_s_setprio(0);
    };

    // prologue: 2 tiles in flight
    stage_K(Kb, Ks[0], bk, 0,  w, lane);  stage_V(Vt, Vs[0], bD, 0,  w, lane);
    stage_K(Kb, Ks[1], bk, 32, w, lane);  stage_V(Vt, Vs[1], bD, 32, w, lane);
    // drain stage(0); lgkm for knS/mkS ds-writes; all waves sync
    asm volatile("s_waitcnt vmcnt(4) lgkmcnt(0)\n\ts_barrier" ::: "memory");
    stage_K(Kb, Ks[2], bk, 64, w, lane);  stage_V(Vt, Vs[2], bD, 64, w, lane);
    do_tile(0, Ks[0], Vs[0]);

    int cur = 1;
    for (int kt = 1; kt < 63; ++kt) {
        // drain own stage(kt) (4 oldest); after barrier all waves' portions done
        asm volatile("s_waitcnt vmcnt(5)\n\ts_barrier" ::: "memory");
        if (kt < 62) {
            int nb = cur + 2; if (nb >= 3) nb -= 3;   // (kt+2) % 3
            stage_K(Kb, Ks[nb], bk, (kt+2)*32, w, lane);
            stage_V(Vt, Vs[nb], bD, (kt+2)*32, w, lane);
        }
        do_tile(kt*32, Ks[cur], Vs[cur]);
        cur = (cur == 2) ? 0 : cur + 1;
    }
    asm volatile("s_waitcnt vmcnt(2)\n\ts_barrier" ::: "memory");
    do_tile(63*32, Ks[0], Vs[0]);   // 63 % 3 == 0

    // epilogue: rowsum butterfly, att_out NT stores
    float inv4[4];
    #pragma unroll
    for (int r = 0; r < 4; ++r) {
        float v = rs[r];
        v += __shfl_xor(v, 1, 16);
        v += __shfl_xor(v, 2, 16);
        v += __shfl_xor(v, 4, 16);
        v += __shfl_xor(v, 8, 16);
        inv4[r] = 1.0f / v;
        if (q16 == 0) rowsum[qrow + quad*4 + r] = v;
    }
    #pragma unroll
    for (int n = 0; n < 16; ++n)
        #pragma unroll
        for (int r = 0; r < 4; ++r)
            __builtin_nontemporal_store(O[n][r] * inv4[r],
                att_out + (size_t)(qrow + quad*4 + r)*D_ + n*16 + q16);
}

// -------- K3: attn = E * (1/rowsum), pure streaming, full occupancy --------
__global__ __launch_bounds__(256) void norm_kernel(
    const unsigned short* __restrict__ Eb,
    const float* __restrict__ rowsum,
    float* __restrict__ attn_out)
{
    const int row = blockIdx.x;
    const int t   = threadIdx.x;
    const float inv = 1.0f / rowsum[row];
    const size_t base = (size_t)row * L_ + t*8;

    s8v e = __builtin_nontemporal_load((const s8v*)(Eb + base));
    f4n o0, o1;
    o0.x = __builtin_bit_cast(float, ((unsigned)(unsigned short)e[0]) << 16) * inv;
    o0.y = __builtin_bit_cast(float, ((unsigned)(unsigned short)e[1]) << 16) * inv;
    o0.z = __builtin_bit_cast(float, ((unsigned)(unsigned short)e[2]) << 16) * inv;
    o0.w = __builtin_bit_cast(float, ((unsigned)(unsigned short)e[3]) << 16) * inv;
    o1.x = __builtin_bit_cast(float, ((unsigned)(unsigned short)e[4]) << 16) * inv;
    o1.y = __builtin_bit_cast(float, ((unsigned)(unsigned short)e[5]) << 16) * inv;
    o1.z = __builtin_bit_cast(float, ((unsigned)(unsigned short)e[6]) << 16) * inv;
    o1.w = __builtin_bit_cast(float, ((unsigned)(unsigned short)e[7]) << 16) * inv;
    __builtin_nontemporal_store(o0, (f4n*)(attn_out + base));
    __builtin_nontemporal_store(o1, (f4n*)(attn_out + base + 4));
}

extern "C" void kernel_launch(void* const* d_in, const int* in_sizes, int n_in,
                              void* d_out, int out_size, void* d_ws, size_t ws_size,
                              hipStream_t stream) {
    (void)in_sizes; (void)n_in; (void)out_size; (void)ws_size;
    const float* x  = (const float*)d_in[0];
    const float* y  = (const float*)d_in[1];
    const unsigned char* mask = (const unsigned char*)d_in[2];
    const float* Wq = (const float*)d_in[3];
    const float* Wk = (const float*)d_in[4];
    const float* Wv = (const float*)d_in[5];

    // ws: Qb | Kb | Vt (bf16) | qn | kn | rowsum (fp32) | Eb (bf16) | Wb (bf16)
    char* ws = (char*)d_ws;
    unsigned short* Qb = (unsigned short*)ws;
    unsigned short* Kb = Qb + (size_t)NROW * D_;
    unsigned short* Vt = Kb + (size_t)NROW * D_;
    float* qn     = (float*)(ws + 3 * (size_t)NROW * D_ * 2);
    float* kn     = qn + NROW;
    float* rowsum = kn + NROW;
    unsigned short* Eb = (unsigned short*)(rowsum + NROW);
    unsigned short* Wb = Eb + (size_t)NROW * L_;

    float* att_out = (float*)d_out;                       // [B, LQ, D]
    float* attn    = att_out + (size_t)NROW * D_;         // [B, LQ, LK]

    wconv_kernel<<<dim3(4, 3), 256, 0, stream>>>(Wq, Wk, Wv, Wb);
    qkv_kernel<<<dim3(512, 2), 256, 0, stream>>>(x, y, Wb, Qb, Kb, Vt, qn, kn);
    attnpv_kernel<<<dim3(16, 16), 512, 0, stream>>>(Qb, Kb, Vt, qn, kn, mask,
                                                    Eb, rowsum, att_out);
    norm_kernel<<<dim3(NROW), 256, 0, stream>>>(Eb, rowsum, attn);
}